// Round 1
// 515.047 us; speedup vs baseline: 1.0549x; 1.0549x over previous
//
#include <hip/hip_runtime.h>
#include <math.h>

typedef __attribute__((ext_vector_type(4))) int   i32x4;
typedef __attribute__((ext_vector_type(4))) float f32x4;

__device__ __forceinline__ float sigmoidf_(float v) {
    return 1.0f / (1.0f + __expf(-v));
}

// 32 rows per wave-iteration (two 16x16 M-tiles), N=128 (8 tiles), K=128 (2 k-steps of 64).
// Matmul on v_mfma_i32_16x16x64_i8; weights live in LDS as pre-packed B fragments.
__global__ __launch_bounds__(256, 3)
void mlgru_kernel(const float* __restrict__ x,
                  const float* __restrict__ hprev,
                  const float* __restrict__ Wf,
                  const float* __restrict__ Wc,
                  const float* __restrict__ Wg,
                  const float* __restrict__ bf,
                  const float* __restrict__ bc,
                  const float* __restrict__ bg,
                  float* __restrict__ out,
                  int nrows)
{
    // B-fragment store: frag = ((g*8 + t)*2 + s)*64 + lane, 16 bytes each. 48 KB total.
    // Lane l holds B[k = s*64 + (l>>4)*16 + byte][n = t*16 + (l&15)], bytes LSB-first.
    __shared__ i32x4 wlds[3 * 8 * 2 * 64];

    const int tid  = threadIdx.x;
    const int lane = tid & 63;
    const int widx = tid >> 6;
    const int lm   = lane & 15;   // A-row / B-col / C-col within a 16-tile
    const int kg   = lane >> 4;   // k-group (0..3)

    // ---- stage sign(W) as int8 MFMA B fragments (one-time, coalesced-ish) ----
    for (int idx = tid; idx < 3 * 8 * 2 * 64; idx += 256) {
        const int l  = idx & 63;
        const int s  = (idx >> 6) & 1;
        const int t  = (idx >> 7) & 7;
        const int g  = idx >> 10;
        const float* Wp = (g == 0) ? Wf : ((g == 1) ? Wc : Wg);
        const int n  = t * 16 + (l & 15);
        const int kb = s * 64 + (l >> 4) * 16;
        i32x4 fr;
        #pragma unroll
        for (int d = 0; d < 4; ++d) {
            const float4 v = *(const float4*)(Wp + n * 128 + kb + d * 4);
            const int b0 = (v.x > 0.f) - (v.x < 0.f);
            const int b1 = (v.y > 0.f) - (v.y < 0.f);
            const int b2 = (v.z > 0.f) - (v.z < 0.f);
            const int b3 = (v.w > 0.f) - (v.w < 0.f);
            fr[d] = (b0 & 0xFF) | ((b1 & 0xFF) << 8) | ((b2 & 0xFF) << 16) | ((b3 & 0xFF) << 24);
        }
        wlds[idx] = fr;
    }

    // per-lane biases for n = t*16 + lm (tiny, L1-resident)
    float vbf[8], vbc[8], vbg[8];
    #pragma unroll
    for (int t = 0; t < 8; ++t) {
        vbf[t] = bf[t * 16 + lm];
        vbc[t] = bc[t * 16 + lm];
        vbg[t] = bg[t * 16 + lm];
    }
    __syncthreads();

    const int gw   = blockIdx.x * 4 + widx;
    const int nw   = gridDim.x * 4;
    const int ngrp = nrows >> 5;               // 32 rows per group
    const long long hoff = (long long)nrows * 128;

    for (int grp = gw; grp < ngrp; grp += nw) {
        const int row0 = grp << 5;

        i32x4 afrag[2][2];   // [mtile][kstep] — A fragments, built in-register
        float invm[2];       // this lane's own row scale (row = mt*16 + lm)

        // ---------- layernorm + quant: lane owns row lm, k in {kg*16..+15, 64+kg*16..+15} ----------
        #pragma unroll
        for (int mt = 0; mt < 2; ++mt) {
            const float* xr = x + (long long)(row0 + mt * 16 + lm) * 128 + kg * 16;
            f32x4 vv[8];
            #pragma unroll
            for (int j = 0; j < 4; ++j) {
                vv[j]     = *(const f32x4*)(xr + j * 4);
                vv[j + 4] = *(const f32x4*)(xr + 64 + j * 4);
            }
            float s = 0.f, ss = 0.f;
            #pragma unroll
            for (int j = 0; j < 8; ++j)
                #pragma unroll
                for (int e = 0; e < 4; ++e) { const float t = vv[j][e]; s += t; ss = fmaf(t, t, ss); }
            s  += __shfl_xor(s, 16);   ss += __shfl_xor(ss, 16);
            s  += __shfl_xor(s, 32);   ss += __shfl_xor(ss, 32);
            const float mean = s * (1.0f / 128.0f);
            const float var  = ss * (1.0f / 128.0f) - mean * mean;
            const float rstd = rsqrtf(var + 1e-8f);
            float am = 0.f;
            #pragma unroll
            for (int j = 0; j < 8; ++j)
                #pragma unroll
                for (int e = 0; e < 4; ++e) {
                    const float t = vv[j][e] - mean;
                    vv[j][e] = t;
                    am = fmaxf(am, fabsf(t));
                }
            am = fmaxf(am, __shfl_xor(am, 16));
            am = fmaxf(am, __shfl_xor(am, 32));
            // q = rint((x-mean) * 127/amax) : rstd cancels between normalize and 127/max|y|
            const float sq = 127.0f / am;
            invm[mt] = am * rstd * (1.0f / 127.0f);   // dequant scale (rstd folded back in)
            #pragma unroll
            for (int s2 = 0; s2 < 2; ++s2) {
                i32x4 fr;
                #pragma unroll
                for (int d = 0; d < 4; ++d) {
                    const int j = s2 * 4 + d;
                    const int q0 = max(-128, min(127, (int)rintf(vv[j][0] * sq)));
                    const int q1 = max(-128, min(127, (int)rintf(vv[j][1] * sq)));
                    const int q2 = max(-128, min(127, (int)rintf(vv[j][2] * sq)));
                    const int q3 = max(-128, min(127, (int)rintf(vv[j][3] * sq)));
                    fr[d] = (q0 & 0xFF) | ((q1 & 0xFF) << 8) | ((q2 & 0xFF) << 16) | ((q3 & 0xFF) << 24);
                }
                afrag[mt][s2] = fr;
            }
        }

        // broadcast row scales into C-layout rows (m = kg*4 + r); source lanes 0..15 hold row=lane
        float invb[2][4];
        #pragma unroll
        for (int mt = 0; mt < 2; ++mt)
            #pragma unroll
            for (int r = 0; r < 4; ++r)
                invb[mt][r] = __shfl(invm[mt], kg * 4 + r);

        // ---------- per n-tile: 12 MFMAs (3 gates x 2 ksteps x 2 mtiles) + fused epilogue ----------
        for (int t = 0; t < 8; ++t) {
            i32x4 acc[3][2];
            #pragma unroll
            for (int g = 0; g < 3; ++g) {
                acc[g][0] = (i32x4){0, 0, 0, 0};
                acc[g][1] = (i32x4){0, 0, 0, 0};
            }
            #pragma unroll
            for (int s2 = 0; s2 < 2; ++s2)
                #pragma unroll
                for (int g = 0; g < 3; ++g) {
                    const i32x4 bfr = wlds[((g * 8 + t) * 2 + s2) * 64 + lane];
                    acc[g][0] = __builtin_amdgcn_mfma_i32_16x16x64_i8(afrag[0][s2], bfr, acc[g][0], 0, 0, 0);
                    acc[g][1] = __builtin_amdgcn_mfma_i32_16x16x64_i8(afrag[1][s2], bfr, acc[g][1], 0, 0, 0);
                }

            // C layout: n = t*16 + lm, m = kg*4 + r
            #pragma unroll
            for (int mt = 0; mt < 2; ++mt)
                #pragma unroll
                for (int r = 0; r < 4; ++r) {
                    const int m = kg * 4 + r;
                    const float inv = invb[mt][r];
                    const long long rbase =
                        (long long)(row0 + mt * 16 + m) * 128 + t * 16 + lm;
                    const float hp = hprev[rbase];
                    const float fx = (float)acc[0][mt][r] * inv + vbf[t];
                    const float cx = (float)acc[1][mt][r] * inv + vbc[t];
                    const float gx = (float)acc[2][mt][r] * inv + vbg[t];
                    const float f  = sigmoidf_(fx);
                    const float c  = cx * sigmoidf_(cx);     // silu
                    const float gg = sigmoidf_(gx);
                    const float h  = f * hp + (1.0f - f) * c;
                    out[rbase]        = gg * h;
                    out[hoff + rbase] = h;
                }
        }
    }
}

extern "C" void kernel_launch(void* const* d_in, const int* in_sizes, int n_in,
                              void* d_out, int out_size, void* d_ws, size_t ws_size,
                              hipStream_t stream) {
    const float* x  = (const float*)d_in[0];
    const float* h  = (const float*)d_in[1];
    const float* Wf = (const float*)d_in[2];
    const float* Wc = (const float*)d_in[3];
    const float* Wg = (const float*)d_in[4];
    const float* bf = (const float*)d_in[5];
    const float* bc = (const float*)d_in[6];
    const float* bg = (const float*)d_in[7];
    float* out = (float*)d_out;
    const int nrows = in_sizes[0] / 128;   // B = 262144 -> 8192 groups of 32 rows

    // 1024 blocks x 4 waves = 4096 waves -> exactly 2 groups per wave
    hipLaunchKernelGGL(mlgru_kernel, dim3(1024), dim3(256), 0, stream,
                       x, h, Wf, Wc, Wg, bf, bc, bg, out, nrows);
}